// Round 8
// baseline (647.799 us; speedup 1.0000x reference)
//
#include <hip/hip_runtime.h>
#include <math.h>

#define E_TOTAL   1000000
#define HDIM      128
#define K1        256   // 2H
#define N1        512   // 4H
#define N2        128   // H
#define M_TILE    32
#define BLOCK     256

typedef _Float16 f16;
typedef _Float16 f16_4  __attribute__((ext_vector_type(4)));
typedef _Float16 f16_8  __attribute__((ext_vector_type(8)));
typedef float    f32_16 __attribute__((ext_vector_type(16)));

// ---------------- prep kernels ----------------
// 32x32x16 fragment packing (A/B frag: lane l holds [row=l&31][k=(l>>5)*8+v]):
// W1F[nt(16)][kc(16)][lane(64)][v(8)] = W1[k=kc*16+(l>>5)*8+v][n=nt*32+(l&31)]
// W2F[nt(4)][kcg(32)][lane(64)][v(8)] = W2[k=kcg*16+(l>>5)*8+v][n=nt*32+(l&31)]
__global__ void prep_weights(const float* __restrict__ W1, const float* __restrict__ W2,
                             f16* __restrict__ W1F, f16* __restrict__ W2F) {
    int t = blockIdx.x * blockDim.x + threadIdx.x;
    const int total1 = K1 * N1;           // 131072
    const int total2 = N1 * N2;           // 65536
    if (t < total1) {
        int v    = t & 7;
        int lane = (t >> 3) & 63;
        int kc   = (t >> 9) & 15;
        int nt   = t >> 13;
        int k = kc * 16 + (lane >> 5) * 8 + v;
        int n = nt * 32 + (lane & 31);
        W1F[t] = (f16)W1[k * N1 + n];
    } else if (t < total1 + total2) {
        int u = t - total1;
        int v    = u & 7;
        int lane = (u >> 3) & 63;
        int kcg  = (u >> 9) & 31;
        int nt   = u >> 14;
        int k = kcg * 16 + (lane >> 5) * 8 + v;
        int n = nt * 32 + (lane & 31);
        W2F[u] = (f16)W2[k * N2 + n];
    }
}

__global__ void prep_emb(const float* __restrict__ emb, f16* __restrict__ emb16) {
    int t = blockIdx.x * blockDim.x + threadIdx.x;   // 3.2M threads, 4 elems each
    float4 f = ((const float4*)emb)[t];
    f16_4 v = { (f16)f.x, (f16)f.y, (f16)f.z, (f16)f.w };
    ((f16_4*)emb16)[t] = v;
}

// ---------------- main kernel ----------------
// R7 structure (quarters + sBF dbuf + fragment-layout LDS) at 256 threads:
//   4 waves = wnt 0..3, 32 edges/block.
//   sAF [kc(16)][lane(64)][8]        = 16 KB  (gathered edges; overlaid by sH2F)
//   sBF [buf(2)][kl(8)][lane(64)][8] = 2 x 8 KB (H1-quarter dbuf)
//   sH2F[kl(8)][lane(64)][8]         =  8 KB  (overlays sAF)
// LDS 32 KB -> 5 blocks/CU = 20 waves (62.5% occupancy); regs ~84 unified.
template <bool F16EMB>
__global__ __launch_bounds__(BLOCK, 4) void edge_mlp_kernel(
    const float* __restrict__ emb,
    const f16*   __restrict__ emb16,
    const int*   __restrict__ eidx,
    const f16*   __restrict__ W1F,
    const float* __restrict__ b1,
    const f16*   __restrict__ W2F,
    const float* __restrict__ b2,
    const float* __restrict__ W3,
    const float* __restrict__ b3,
    float* __restrict__ out)
{
    __shared__ __align__(16) f16 sAF[16 * 64 * 8];       // 16 KB
    __shared__ __align__(16) f16 sBF[2][8 * 64 * 8];     // 2 x 8 KB
    f16* sH2F = sAF;                                     // 8 KB overlay

    const int tid = threadIdx.x;
    const int e0  = blockIdx.x * M_TILE;

    // ---- Phase 0: gather emb[col]||emb[row] -> sAF (fragment layout) ----
    // thread: m=tid>>3 (edge 0..31), side=(tid>>2)&1, sub=tid&3; g=side*8+sub*2+j
    // piece (m, kc=g, lh): 8 f16 at sAF[((g)*64 + lh*32 + m)*8]
    {
        const int m    = tid >> 3;
        const int side = (tid >> 2) & 1;
        const int sub  = tid & 3;
        const int node = eidx[side * E_TOTAL + e0 + m];
        if (F16EMB) {
            const f16* src = emb16 + (size_t)node * HDIM;
            #pragma unroll
            for (int j = 0; j < 2; ++j) {
                const int g = side * 8 + sub * 2 + j;
                const int koff = (sub * 2 + j) * 16;       // within node row
                #pragma unroll
                for (int lh = 0; lh < 2; ++lh) {
                    f16_8 v = *(const f16_8*)(src + koff + lh * 8);
                    *(f16_8*)(sAF + ((g * 64 + lh * 32 + m) << 3)) = v;
                }
            }
        } else {
            const float* src = emb + (size_t)node * HDIM;
            #pragma unroll
            for (int j = 0; j < 2; ++j) {
                const int g = side * 8 + sub * 2 + j;
                const int koff = (sub * 2 + j) * 16;
                #pragma unroll
                for (int lh = 0; lh < 2; ++lh) {
                    float4 fa = *(const float4*)(src + koff + lh * 8);
                    float4 fb = *(const float4*)(src + koff + lh * 8 + 4);
                    f16_8 v = { (f16)fa.x, (f16)fa.y, (f16)fa.z, (f16)fa.w,
                                (f16)fb.x, (f16)fb.y, (f16)fb.z, (f16)fb.w };
                    *(f16_8*)(sAF + ((g * 64 + lh * 32 + m) << 3)) = v;
                }
            }
        }
    }
    __syncthreads();

    const int wnt  = tid >> 6;     // wave 0..3 = n-tile within quarter / P2 n-strip
    const int lane = tid & 63;
    const int l31  = lane & 31;
    const int lh   = lane >> 5;    // 0/1

    f32_16 acc2 = {0.f};   // P2 accumulator, persists across all 4 quarters

    // ---- Region 0: P1(0) only -> sBF[0] ----
    {
        f32_16 acc1 = {0.f};
        const int nt = wnt;                          // quarter 0, n-tile wnt
        #pragma unroll
        for (int kc = 0; kc < 16; ++kc) {
            f16_8 ef = *(const f16_8*)(sAF + ((kc * 64 + lane) << 3));
            f16_8 wf = *(const f16_8*)(W1F + (((nt * 16 + kc) * 64 + lane) << 3));
            acc1 = __builtin_amdgcn_mfma_f32_32x32x16_f16(wf, ef, acc1, 0, 0, 0);
        }
        // epilogue: value (edge=l31, n1q = wnt*32+lh*4+g*8+i) -> frag write
        f16* bcur = &sBF[0][0];
        #pragma unroll
        for (int g = 0; g < 4; ++g) {
            const int wnl = wnt * 32 + lh * 4 + g * 8;
            const float4 bv = *(const float4*)(b1 + wnl);   // quarter 0
            f16_4 hv;
            #pragma unroll
            for (int i = 0; i < 4; ++i) {
                float v = acc1[g * 4 + i] + ((const float*)&bv)[i];
                hv[i] = (f16)(v > 0.f ? v : 0.f);
            }
            const int kl = wnt * 2 + (g >> 1);
            *(f16_4*)(bcur + (((kl * 64 + (g & 1) * 32 + l31) << 3) + lh * 4)) = hv;
        }
    }
    __syncthreads();

    // ---- Regions 1..3: P1(q) -> sBF[q&1] interleaved with P2(q-1) <- sBF[(q-1)&1] ----
    #pragma unroll
    for (int q = 1; q < 4; ++q) {
        f32_16 acc1 = {0.f};
        const int nt = q * 4 + wnt;
        const f16* bprev = &sBF[(q - 1) & 1][0];
        #pragma unroll
        for (int kc = 0; kc < 16; ++kc) {
            f16_8 ef = *(const f16_8*)(sAF + ((kc * 64 + lane) << 3));
            f16_8 wf = *(const f16_8*)(W1F + (((nt * 16 + kc) * 64 + lane) << 3));
            acc1 = __builtin_amdgcn_mfma_f32_32x32x16_f16(wf, ef, acc1, 0, 0, 0);
            if (kc < 8) {
                const int kcg = (q - 1) * 8 + kc;            // global k-chunk for W2
                f16_8 ef2 = *(const f16_8*)(bprev + ((kc * 64 + lane) << 3));
                f16_8 wf2 = *(const f16_8*)(W2F + (((wnt * 32 + kcg) * 64 + lane) << 3));
                acc2 = __builtin_amdgcn_mfma_f32_32x32x16_f16(wf2, ef2, acc2, 0, 0, 0);
            }
        }
        // P1(q) epilogue -> sBF[q&1]
        f16* bcur = &sBF[q & 1][0];
        #pragma unroll
        for (int g = 0; g < 4; ++g) {
            const int wnl = wnt * 32 + lh * 4 + g * 8;
            const float4 bv = *(const float4*)(b1 + q * 128 + wnl);
            f16_4 hv;
            #pragma unroll
            for (int i = 0; i < 4; ++i) {
                float v = acc1[g * 4 + i] + ((const float*)&bv)[i];
                hv[i] = (f16)(v > 0.f ? v : 0.f);
            }
            const int kl = wnt * 2 + (g >> 1);
            *(f16_4*)(bcur + (((kl * 64 + (g & 1) * 32 + l31) << 3) + lh * 4)) = hv;
        }
        __syncthreads();
    }

    // ---- Final P2(3) <- sBF[1] ----
    {
        const f16* bprev = &sBF[1][0];
        #pragma unroll
        for (int kc = 0; kc < 8; ++kc) {
            const int kcg = 24 + kc;
            f16_8 ef2 = *(const f16_8*)(bprev + ((kc * 64 + lane) << 3));
            f16_8 wf2 = *(const f16_8*)(W2F + (((wnt * 32 + kcg) * 64 + lane) << 3));
            acc2 = __builtin_amdgcn_mfma_f32_32x32x16_f16(wf2, ef2, acc2, 0, 0, 0);
        }
    }

    // ---- P2 epilogue -> sH2F (fragment layout, overlays sAF; all sAF reads
    //      completed before the q=3 barrier) ----
    {
        #pragma unroll
        for (int g = 0; g < 4; ++g) {
            const int wn = wnt * 32 + lh * 4 + g * 8;
            const float4 bv = *(const float4*)(b2 + wn);
            f16_4 hv;
            #pragma unroll
            for (int i = 0; i < 4; ++i) {
                float v = acc2[g * 4 + i] + ((const float*)&bv)[i];
                hv[i] = (f16)(v > 0.f ? v : 0.f);
            }
            const int kl = wnt * 2 + (g >> 1);
            *(f16_4*)(sH2F + (((kl * 64 + (g & 1) * 32 + l31) << 3) + lh * 4)) = hv;
        }
    }
    __syncthreads();

    // ---- Phase 3: logit = H2 @ W3 + b3 ; sigmoid ----
    // thread: m=tid>>3 (edge 0..31), j=tid&7 (16-k chunk). H2[m][j*16+lh'*8+v]
    // is at sH2F[(j*64 + lh'*32 + m)*8 + v].
    {
        const int m = tid >> 3;
        const int j = tid & 7;
        f16_8 a = *(const f16_8*)(sH2F + ((j * 64 + m) << 3));
        f16_8 b = *(const f16_8*)(sH2F + ((j * 64 + 32 + m) << 3));
        const float4* w3v = (const float4*)(W3 + j * 16);
        float4 w0 = w3v[0], w1 = w3v[1], w2 = w3v[2], w3 = w3v[3];
        float s = 0.f;
        s += (float)a[0]*w0.x + (float)a[1]*w0.y + (float)a[2]*w0.z + (float)a[3]*w0.w;
        s += (float)a[4]*w1.x + (float)a[5]*w1.y + (float)a[6]*w1.z + (float)a[7]*w1.w;
        s += (float)b[0]*w2.x + (float)b[1]*w2.y + (float)b[2]*w2.z + (float)b[3]*w2.w;
        s += (float)b[4]*w3.x + (float)b[5]*w3.y + (float)b[6]*w3.z + (float)b[7]*w3.w;
        s += __shfl_xor(s, 1);
        s += __shfl_xor(s, 2);
        s += __shfl_xor(s, 4);
        if (j == 0) {
            const float logit = s + b3[0];
            out[e0 + m] = 1.0f / (1.0f + __expf(-logit));
        }
    }
}

extern "C" void kernel_launch(void* const* d_in, const int* in_sizes, int n_in,
                              void* d_out, int out_size, void* d_ws, size_t ws_size,
                              hipStream_t stream) {
    const float* emb  = (const float*)d_in[0];
    const int*   eidx = (const int*)d_in[1];
    const float* W1   = (const float*)d_in[2];
    const float* b1   = (const float*)d_in[3];
    const float* W2   = (const float*)d_in[4];
    const float* b2   = (const float*)d_in[5];
    const float* W3   = (const float*)d_in[6];
    const float* b3   = (const float*)d_in[7];
    float* out = (float*)d_out;

    const size_t wbytes   = (size_t)(K1 * N1 + N1 * N2) * sizeof(f16);   // 384 KB
    const size_t embbytes = (size_t)100000 * HDIM * sizeof(f16);         // 25.6 MB

    f16* W1F = (f16*)d_ws;
    f16* W2F = W1F + K1 * N1;

    const int prep_total = K1 * N1 + N1 * N2;
    prep_weights<<<(prep_total + 255) / 256, 256, 0, stream>>>(W1, W2, W1F, W2F);

    if (ws_size >= wbytes + embbytes) {
        f16* emb16 = W2F + N1 * N2;
        const int cvt_threads = 100000 * HDIM / 4;   // 3.2M
        prep_emb<<<cvt_threads / 256, 256, 0, stream>>>(emb, emb16);
        edge_mlp_kernel<true><<<E_TOTAL / M_TILE, BLOCK, 0, stream>>>(
            emb, emb16, eidx, W1F, b1, W2F, b2, W3, b3, out);
    } else {
        edge_mlp_kernel<false><<<E_TOTAL / M_TILE, BLOCK, 0, stream>>>(
            emb, (const f16*)nullptr, eidx, W1F, b1, W2F, b2, W3, b3, out);
    }
}

// Round 9
// 559.505 us; speedup vs baseline: 1.1578x; 1.1578x over previous
//
#include <hip/hip_runtime.h>
#include <math.h>

#define E_TOTAL   1000000
#define HDIM      128
#define K1        256   // 2H
#define N1        512   // 4H
#define N2        128   // H
#define M_TILE    64
#define BLOCK     256

typedef _Float16 f16;
typedef _Float16 f16_4  __attribute__((ext_vector_type(4)));
typedef _Float16 f16_8  __attribute__((ext_vector_type(8)));
typedef float    f32_16 __attribute__((ext_vector_type(16)));

// ---------------- prep kernels ----------------
// 32x32x16 fragment packing (A/B frag: lane l holds [row=l&31][k=(l>>5)*8+v]):
// W1F[nt(16)][kc(16)][lane(64)][v(8)] = W1[k=kc*16+(l>>5)*8+v][n=nt*32+(l&31)]
// W2F[nt(4)][kcg(32)][lane(64)][v(8)] = W2[k=kcg*16+(l>>5)*8+v][n=nt*32+(l&31)]
__global__ void prep_weights(const float* __restrict__ W1, const float* __restrict__ W2,
                             f16* __restrict__ W1F, f16* __restrict__ W2F) {
    int t = blockIdx.x * blockDim.x + threadIdx.x;
    const int total1 = K1 * N1;           // 131072
    const int total2 = N1 * N2;           // 65536
    if (t < total1) {
        int v    = t & 7;
        int lane = (t >> 3) & 63;
        int kc   = (t >> 9) & 15;
        int nt   = t >> 13;
        int k = kc * 16 + (lane >> 5) * 8 + v;
        int n = nt * 32 + (lane & 31);
        W1F[t] = (f16)W1[k * N1 + n];
    } else if (t < total1 + total2) {
        int u = t - total1;
        int v    = u & 7;
        int lane = (u >> 3) & 63;
        int kcg  = (u >> 9) & 31;
        int nt   = u >> 14;
        int k = kcg * 16 + (lane >> 5) * 8 + v;
        int n = nt * 32 + (lane & 31);
        W2F[u] = (f16)W2[k * N2 + n];
    }
}

__global__ void prep_emb(const float* __restrict__ emb, f16* __restrict__ emb16) {
    int t = blockIdx.x * blockDim.x + threadIdx.x;   // 3.2M threads, 4 elems each
    float4 f = ((const float4*)emb)[t];
    f16_4 v = { (f16)f.x, (f16)f.y, (f16)f.z, (f16)f.w };
    ((f16_4*)emb16)[t] = v;
}

// ---------------- main kernel ----------------
// R7/R8 structure (quarters + dbuf + fragment-layout LDS) with IN-REGISTER
// weight reuse: 64 edges/block, 256 threads = 4 waves (wnt 0..3); each wave
// carries TWO edge tiles (et=0,1) so every wf load feeds 2 MFMAs.
//   sAF [et(2)][kc(16)][lane(64)][8]        = 32 KB (gather; overlaid by sH2F)
//   sBF [buf(2)][et(2)][kl(8)][lane(64)][8] = 2 x 16 KB (H1-quarter dbuf)
//   sH2F[et(2)][kl(8)][lane(64)][8]         = 16 KB (overlays sAF)
// LDS 64 KB -> 2 blocks/CU; regs ~119 unified -> launch_bounds(256,2), no spill.
template <bool F16EMB>
__global__ __launch_bounds__(BLOCK, 2) void edge_mlp_kernel(
    const float* __restrict__ emb,
    const f16*   __restrict__ emb16,
    const int*   __restrict__ eidx,
    const f16*   __restrict__ W1F,
    const float* __restrict__ b1,
    const f16*   __restrict__ W2F,
    const float* __restrict__ b2,
    const float* __restrict__ W3,
    const float* __restrict__ b3,
    float* __restrict__ out)
{
    __shared__ __align__(16) f16 sAF[2 * 16 * 64 * 8];      // 32 KB
    __shared__ __align__(16) f16 sBF[2][2 * 8 * 64 * 8];    // 2 x 16 KB
    f16* sH2F = sAF;                                        // 16 KB overlay

    const int tid = threadIdx.x;
    const int e0  = blockIdx.x * M_TILE;

    // ---- Phase 0: gather emb[col]||emb[row] -> sAF (fragment layout) ----
    // thread: m=tid>>2 (edge 0..63), side=(tid>>1)&1, sub=tid&1; 8x16B each.
    {
        const int m    = tid >> 2;
        const int side = (tid >> 1) & 1;
        const int sub  = tid & 1;
        const int met  = m >> 5;
        const int m31  = m & 31;
        const int node = eidx[side * E_TOTAL + e0 + m];
        if (F16EMB) {
            const f16* src = emb16 + (size_t)node * HDIM;
            #pragma unroll
            for (int j = 0; j < 4; ++j) {
                const int g = side * 8 + sub * 4 + j;
                const int koff = (sub * 4 + j) * 16;       // within node row
                #pragma unroll
                for (int lh = 0; lh < 2; ++lh) {
                    f16_8 v = *(const f16_8*)(src + koff + lh * 8);
                    *(f16_8*)(sAF + (((met * 16 + g) * 64 + lh * 32 + m31) << 3)) = v;
                }
            }
        } else {
            const float* src = emb + (size_t)node * HDIM;
            #pragma unroll
            for (int j = 0; j < 4; ++j) {
                const int g = side * 8 + sub * 4 + j;
                const int koff = (sub * 4 + j) * 16;
                #pragma unroll
                for (int lh = 0; lh < 2; ++lh) {
                    float4 fa = *(const float4*)(src + koff + lh * 8);
                    float4 fb = *(const float4*)(src + koff + lh * 8 + 4);
                    f16_8 v = { (f16)fa.x, (f16)fa.y, (f16)fa.z, (f16)fa.w,
                                (f16)fb.x, (f16)fb.y, (f16)fb.z, (f16)fb.w };
                    *(f16_8*)(sAF + (((met * 16 + g) * 64 + lh * 32 + m31) << 3)) = v;
                }
            }
        }
    }
    __syncthreads();

    const int wnt  = tid >> 6;     // wave 0..3 = n-tile within quarter / P2 n-strip
    const int lane = tid & 63;
    const int l31  = lane & 31;
    const int lh   = lane >> 5;    // 0/1

    f32_16 acc2[2] = {{0.f}, {0.f}};   // P2 accumulators (both edge tiles)

    // ---- Region 0: P1(0) only -> sBF[0] ----
    {
        f32_16 acc1[2] = {{0.f}, {0.f}};
        const int nt = wnt;                          // quarter 0
        #pragma unroll
        for (int kc = 0; kc < 16; ++kc) {
            f16_8 wf = *(const f16_8*)(W1F + (((nt * 16 + kc) * 64 + lane) << 3));
            #pragma unroll
            for (int et = 0; et < 2; ++et) {
                f16_8 ef = *(const f16_8*)(sAF + (((et * 16 + kc) * 64 + lane) << 3));
                acc1[et] = __builtin_amdgcn_mfma_f32_32x32x16_f16(wf, ef, acc1[et], 0, 0, 0);
            }
        }
        f16* bcur = &sBF[0][0];
        #pragma unroll
        for (int et = 0; et < 2; ++et) {
            #pragma unroll
            for (int g = 0; g < 4; ++g) {
                const int wnl = wnt * 32 + lh * 4 + g * 8;
                const float4 bv = *(const float4*)(b1 + wnl);   // quarter 0
                f16_4 hv;
                #pragma unroll
                for (int i = 0; i < 4; ++i) {
                    float v = acc1[et][g * 4 + i] + ((const float*)&bv)[i];
                    hv[i] = (f16)(v > 0.f ? v : 0.f);
                }
                const int kl = wnt * 2 + (g >> 1);
                *(f16_4*)(bcur + ((((et * 8 + kl) * 64 + (g & 1) * 32 + l31) << 3) + lh * 4)) = hv;
            }
        }
    }
    __syncthreads();

    // ---- Regions 1..3: P1(q) -> sBF[q&1] interleaved with P2(q-1) <- sBF[(q-1)&1] ----
    #pragma unroll
    for (int q = 1; q < 4; ++q) {
        f32_16 acc1[2] = {{0.f}, {0.f}};
        const int nt = q * 4 + wnt;
        const f16* bprev = &sBF[(q - 1) & 1][0];
        #pragma unroll
        for (int kc = 0; kc < 16; ++kc) {
            f16_8 wf = *(const f16_8*)(W1F + (((nt * 16 + kc) * 64 + lane) << 3));
            #pragma unroll
            for (int et = 0; et < 2; ++et) {
                f16_8 ef = *(const f16_8*)(sAF + (((et * 16 + kc) * 64 + lane) << 3));
                acc1[et] = __builtin_amdgcn_mfma_f32_32x32x16_f16(wf, ef, acc1[et], 0, 0, 0);
            }
            if (kc < 8) {
                const int kcg = (q - 1) * 8 + kc;            // global k-chunk for W2
                f16_8 wf2 = *(const f16_8*)(W2F + (((wnt * 32 + kcg) * 64 + lane) << 3));
                #pragma unroll
                for (int et = 0; et < 2; ++et) {
                    f16_8 ef2 = *(const f16_8*)(bprev + (((et * 8 + kc) * 64 + lane) << 3));
                    acc2[et] = __builtin_amdgcn_mfma_f32_32x32x16_f16(wf2, ef2, acc2[et], 0, 0, 0);
                }
            }
        }
        // P1(q) epilogue -> sBF[q&1]
        f16* bcur = &sBF[q & 1][0];
        #pragma unroll
        for (int et = 0; et < 2; ++et) {
            #pragma unroll
            for (int g = 0; g < 4; ++g) {
                const int wnl = wnt * 32 + lh * 4 + g * 8;
                const float4 bv = *(const float4*)(b1 + q * 128 + wnl);
                f16_4 hv;
                #pragma unroll
                for (int i = 0; i < 4; ++i) {
                    float v = acc1[et][g * 4 + i] + ((const float*)&bv)[i];
                    hv[i] = (f16)(v > 0.f ? v : 0.f);
                }
                const int kl = wnt * 2 + (g >> 1);
                *(f16_4*)(bcur + ((((et * 8 + kl) * 64 + (g & 1) * 32 + l31) << 3) + lh * 4)) = hv;
            }
        }
        __syncthreads();
    }

    // ---- Final P2(3) <- sBF[1] ----
    {
        const f16* bprev = &sBF[1][0];
        #pragma unroll
        for (int kc = 0; kc < 8; ++kc) {
            const int kcg = 24 + kc;
            f16_8 wf2 = *(const f16_8*)(W2F + (((wnt * 32 + kcg) * 64 + lane) << 3));
            #pragma unroll
            for (int et = 0; et < 2; ++et) {
                f16_8 ef2 = *(const f16_8*)(bprev + (((et * 8 + kc) * 64 + lane) << 3));
                acc2[et] = __builtin_amdgcn_mfma_f32_32x32x16_f16(wf2, ef2, acc2[et], 0, 0, 0);
            }
        }
    }

    // ---- P2 epilogue -> sH2F (overlays sAF; all sAF reads done pre-q3-barrier) ----
    {
        #pragma unroll
        for (int et = 0; et < 2; ++et) {
            #pragma unroll
            for (int g = 0; g < 4; ++g) {
                const int wn = wnt * 32 + lh * 4 + g * 8;
                const float4 bv = *(const float4*)(b2 + wn);
                f16_4 hv;
                #pragma unroll
                for (int i = 0; i < 4; ++i) {
                    float v = acc2[et][g * 4 + i] + ((const float*)&bv)[i];
                    hv[i] = (f16)(v > 0.f ? v : 0.f);
                }
                const int kl = wnt * 2 + (g >> 1);
                *(f16_4*)(sH2F + ((((et * 8 + kl) * 64 + (g & 1) * 32 + l31) << 3) + lh * 4)) = hv;
            }
        }
    }
    __syncthreads();

    // ---- Phase 3: logit = H2 @ W3 + b3 ; sigmoid ----
    // thread: m=tid>>2 (edge 0..63), j=tid&3 (32-k slice).
    // H2[m][kl*16+lhp*8+v] at sH2F[((met*8+kl)*64 + lhp*32 + m31)*8 + v].
    {
        const int m   = tid >> 2;
        const int j   = tid & 3;
        const int met = m >> 5;
        const int m31 = m & 31;
        float s = 0.f;
        #pragma unroll
        for (int jj = 0; jj < 2; ++jj) {
            const int kl = j * 2 + jj;
            f16_8 a = *(const f16_8*)(sH2F + (((met * 8 + kl) * 64 + m31) << 3));
            f16_8 b = *(const f16_8*)(sH2F + (((met * 8 + kl) * 64 + 32 + m31) << 3));
            const float4* w3v = (const float4*)(W3 + kl * 16);
            float4 w0 = w3v[0], w1 = w3v[1], w2 = w3v[2], w3q = w3v[3];
            s += (float)a[0]*w0.x + (float)a[1]*w0.y + (float)a[2]*w0.z + (float)a[3]*w0.w;
            s += (float)a[4]*w1.x + (float)a[5]*w1.y + (float)a[6]*w1.z + (float)a[7]*w1.w;
            s += (float)b[0]*w2.x + (float)b[1]*w2.y + (float)b[2]*w2.z + (float)b[3]*w2.w;
            s += (float)b[4]*w3q.x + (float)b[5]*w3q.y + (float)b[6]*w3q.z + (float)b[7]*w3q.w;
        }
        s += __shfl_xor(s, 1);
        s += __shfl_xor(s, 2);
        if (j == 0) {
            const float logit = s + b3[0];
            out[e0 + m] = 1.0f / (1.0f + __expf(-logit));
        }
    }
}

extern "C" void kernel_launch(void* const* d_in, const int* in_sizes, int n_in,
                              void* d_out, int out_size, void* d_ws, size_t ws_size,
                              hipStream_t stream) {
    const float* emb  = (const float*)d_in[0];
    const int*   eidx = (const int*)d_in[1];
    const float* W1   = (const float*)d_in[2];
    const float* b1   = (const float*)d_in[3];
    const float* W2   = (const float*)d_in[4];
    const float* b2   = (const float*)d_in[5];
    const float* W3   = (const float*)d_in[6];
    const float* b3   = (const float*)d_in[7];
    float* out = (float*)d_out;

    const size_t wbytes   = (size_t)(K1 * N1 + N1 * N2) * sizeof(f16);   // 384 KB
    const size_t embbytes = (size_t)100000 * HDIM * sizeof(f16);         // 25.6 MB

    f16* W1F = (f16*)d_ws;
    f16* W2F = W1F + K1 * N1;

    const int prep_total = K1 * N1 + N1 * N2;
    prep_weights<<<(prep_total + 255) / 256, 256, 0, stream>>>(W1, W2, W1F, W2F);

    if (ws_size >= wbytes + embbytes) {
        f16* emb16 = W2F + N1 * N2;
        const int cvt_threads = 100000 * HDIM / 4;   // 3.2M
        prep_emb<<<cvt_threads / 256, 256, 0, stream>>>(emb, emb16);
        edge_mlp_kernel<true><<<E_TOTAL / M_TILE, BLOCK, 0, stream>>>(
            emb, emb16, eidx, W1F, b1, W2F, b2, W3, b3, out);
    } else {
        edge_mlp_kernel<false><<<E_TOTAL / M_TILE, BLOCK, 0, stream>>>(
            emb, (const f16*)nullptr, eidx, W1F, b1, W2F, b2, W3, b3, out);
    }
}